// Round 6
// baseline (117.329 us; speedup 1.0000x reference)
//
#include <hip/hip_runtime.h>

// YOLOv1 loss: N=8192, S=7, C=30 -> 401408 cells, 96.4 MB read, scalar out.
// Round 6: guard-free block-cooperative register staging.
//   - 1568 blocks x 256 threads, 256 cells/block. LDS = 3840 float4
//     (p: 1920, t: 1920) = 61440 B -> 2 blocks/CU, 16 waves/CU.
//   - Staging: 15 straight-line global_load_dwordx4 per thread (branchless
//     p/t pointer select; 1920 = 7.5*256 aligns to wave boundaries so every
//     wave instruction is a contiguous 1024-B segment), then 15
//     ds_write_b128, one barrier. Compiler emits progressive vmcnt(N) —
//     no divergent guards to serialize it (R2's mistake), no inline-asm
//     vmcnt the compiler would defeat (R3/R5's mistake, per m131/m135).
//   - Compute: thread tid = cell tid, 30 float2 LDS reads (stride 120 B:
//     4-way bank alias on reads, acceptable), ~120 VALU ops, block reduce,
//     one atomicAdd per block.

#define NCH 30
#define CELLS_PER_SAMPLE 49
#define CPB 256                       // cells per block
#define F4_PER_ARR 1920               // float4 per array per block
#define F4_TOTAL  3840                // p + t
#define NLOAD 15                      // float4 loads per thread

__device__ __forceinline__ float iou_f(float a0, float a1, float a2, float a3,
                                       float b0, float b1, float b2, float b3) {
    float xl = fmaxf(a0, b0);
    float yt = fmaxf(a1, b1);
    float xr = fminf(a2, b2);
    float yb = fminf(a3, b3);
    float ix = fmaxf(xr - xl, 0.0f);
    float iy = fmaxf(yb - yt, 0.0f);
    float inter = ix * iy;
    float aa = fabsf((a2 - a0) * (a3 - a1));
    float ba = fabsf((b2 - b0) * (b3 - b1));
    return inter / (aa + ba - inter + 1e-7f);
}

__device__ __forceinline__ float cell_loss_f(const float* __restrict__ pv,
                                             const float* __restrict__ tv,
                                             int cell) {
    int rem = cell % CELLS_PER_SAMPLE;
    int ci = rem / 7;   // row
    int cj = rem % 7;   // col

    float ltx = (float)cj / 7.0f;
    float lty = (float)ci / 7.0f;

    float coord = (tv[4] > 0.0f) ? 1.0f : 0.0f;
    float noobj = (tv[4] == 0.0f) ? 1.0f : 0.0f;

    // predicted box 1
    float b1x1 = ltx + pv[0] / 7.0f - pv[2] * 0.5f;
    float b1y1 = lty + pv[1] / 7.0f - pv[3] * 0.5f;
    float b1x2 = pv[2] + b1x1;
    float b1y2 = pv[3] + b1y1;

    // predicted box 2 (faithful: p[5:7]*(1/S - 0.5))
    const float C2 = (float)(1.0 / 7.0 - 0.5);
    float b2x1 = ltx + pv[5] * C2;
    float b2y1 = lty + pv[6] * C2;
    float b2x2 = pv[7] + b2x1;
    float b2y2 = pv[8] + b2y1;

    // target box
    float tbx1 = ltx + tv[0] / 7.0f - tv[2] * 0.5f;
    float tby1 = lty + tv[1] / 7.0f - tv[3] * 0.5f;
    float tbx2 = tv[2] + tbx1;
    float tby2 = tv[3] + tby1;

    float iou1 = iou_f(b1x1, b1y1, b1x2, b1y2, tbx1, tby1, tbx2, tby2);
    float iou2 = iou_f(b2x1, b2y1, b2x2, b2y2, tbx1, tby1, tbx2, tby2);

    bool sel = (iou1 >= iou2);
    float bx = sel ? pv[0] : pv[5];
    float by = sel ? pv[1] : pv[6];
    float bw = sel ? pv[2] : pv[7];
    float bh = sel ? pv[3] : pv[8];
    float bc = sel ? pv[4] : pv[9];

    float dx = bx - tv[0];
    float dy = by - tv[1];
    float xy_se = dx * dx + dy * dy;

    float sw = (bw > 0.0f) ? 1.0f : ((bw < 0.0f) ? -1.0f : 0.0f);
    float sh = (bh > 0.0f) ? 1.0f : ((bh < 0.0f) ? -1.0f : 0.0f);
    float dw = sw * sqrtf(fabsf(bw)) - sqrtf(tv[2]);
    float dh = sh * sqrtf(fabsf(bh)) - sqrtf(tv[3]);
    float wh_se = dw * dw + dh * dh;

    float mio = fmaxf(iou1, iou2);
    float dob = mio - bc;
    float obj_se = dob * dob;

    float d4 = pv[4] - tv[4];
    float d9 = pv[9] - tv[9];
    float noobj_se = d4 * d4 + d9 * d9;

    float lab = 0.0f;
    #pragma unroll
    for (int k = 10; k < NCH; ++k) {
        float d = pv[k] - tv[k];
        lab += d * d;
    }

    return coord * (5.0f * (xy_se + wh_se) + obj_se + lab)
         + 0.5f * noobj * noobj_se;
}

__global__ __launch_bounds__(256, 2) void yolo_loss_kernel(
    const float4* __restrict__ p4, const float4* __restrict__ t4,
    float* __restrict__ out, float inv_n)
{
    __shared__ float4 lds[F4_TOTAL];        // 61440 B: [p 1920 | t 1920]
    __shared__ float wave_sums[4];

    const int tid = threadIdx.x;
    const float4* __restrict__ pb = p4 + (size_t)blockIdx.x * F4_PER_ARR;
    const float4* __restrict__ tb = t4 + (size_t)blockIdx.x * F4_PER_ARR;

    // ---- stage: 15 batched loads, branchless p/t select ----
    float4 r[NLOAD];
    #pragma unroll
    for (int i = 0; i < NLOAD; ++i) {
        int idx = tid + i * CPB;            // 0 .. 3839, exact
        const float4* src = (idx < F4_PER_ARR) ? (pb + idx)
                                               : (tb + (idx - F4_PER_ARR));
        r[i] = *src;
    }
    #pragma unroll
    for (int i = 0; i < NLOAD; ++i)
        lds[tid + i * CPB] = r[i];
    __syncthreads();

    // ---- compute: cell tid from LDS ----
    const float* pvp = (const float*)lds + tid * NCH;                 // p area
    const float* tvp = (const float*)lds + F4_PER_ARR * 4 + tid * NCH; // t area

    float pv[NCH], tv[NCH];
    #pragma unroll
    for (int k = 0; k < NCH / 2; ++k) {
        float2 a = ((const float2*)pvp)[k];
        float2 b = ((const float2*)tvp)[k];
        pv[2 * k] = a.x; pv[2 * k + 1] = a.y;
        tv[2 * k] = b.x; tv[2 * k + 1] = b.y;
    }

    float acc = cell_loss_f(pv, tv, blockIdx.x * CPB + tid) * inv_n;

    // ---- reduce: wave shuffle -> LDS -> one atomic per block ----
    #pragma unroll
    for (int off = 32; off > 0; off >>= 1)
        acc += __shfl_down(acc, off, 64);

    int lane = tid & 63;
    int wid  = tid >> 6;
    if (lane == 0) wave_sums[wid] = acc;
    __syncthreads();
    if (tid == 0) {
        float s = wave_sums[0] + wave_sums[1] + wave_sums[2] + wave_sums[3];
        atomicAdd(out, s);
    }
}

extern "C" void kernel_launch(void* const* d_in, const int* in_sizes, int n_in,
                              void* d_out, int out_size, void* d_ws, size_t ws_size,
                              hipStream_t stream) {
    const float4* p = (const float4*)d_in[0];   // modely [N,7,7,30] f32
    const float4* t = (const float4*)d_in[1];   // targety [N,7,7,30] f32
    float* out = (float*)d_out;

    int ncells = in_sizes[0] / NCH;             // 401408
    int nsamples = ncells / CELLS_PER_SAMPLE;   // 8192
    int blocks = ncells / CPB;                  // 1568, exact

    // d_out is poisoned before every timed launch — zero it first.
    hipMemsetAsync(out, 0, sizeof(float) * (size_t)out_size, stream);

    yolo_loss_kernel<<<blocks, 256, 0, stream>>>(
        p, t, out, 1.0f / (float)nsamples);
}